// Round 7
// baseline (380.234 us; speedup 1.0000x reference)
//
#include <hip/hip_runtime.h>
#include <hip/hip_bf16.h>

#define T_SEQ 1024
#define D_MODEL 512
#define N_HEADS 8
#define D_HEAD 64
// 0.125 (1/sqrt(64)) * log2(e): scores computed directly in exp2 domain
#define KSCALE 0.1803368801111244f

typedef unsigned short ushort_t;
typedef short s16x8 __attribute__((ext_vector_type(8)));
typedef float f32x4 __attribute__((ext_vector_type(4)));

__device__ inline f32x4 mfma16(s16x8 a, s16x8 b, f32x4 c) {
    return __builtin_amdgcn_mfma_f32_16x16x32_bf16(a, b, c, 0, 0, 0);
}

__device__ inline ushort_t f2bf(float f) {   // RTNE float->bf16
    union { float f; unsigned u; } v; v.f = f;
    unsigned r = v.u + 0x7FFFu + ((v.u >> 16) & 1u);
    return (ushort_t)(r >> 16);
}
__device__ inline float bf2f(short s) {
    union { unsigned u; float f; } t; t.u = ((unsigned)(unsigned short)s) << 16; return t.f;
}
__device__ inline void cvt4(const float4 f, ushort_t* t) {
    t[0] = f2bf(f.x); t[1] = f2bf(f.y); t[2] = f2bf(f.z); t[3] = f2bf(f.w);
}
__device__ inline s16x8 pack8(const ushort_t* t) {
    s16x8 r;
    #pragma unroll
    for (int e = 0; e < 8; ++e) r[e] = (short)t[e];
    return r;
}

// XOR-swizzled LDS index for 64-u16-wide buffers: 16B chunk ^= (row & 7).
// Frag reads (chunk = 4ks+quad, row%8 = lanelo%8) become bank-conflict-free.
// Involution: physical chunk = logical chunk ^ (row&7) on BOTH write and read.
__device__ inline int lidx(int row, int chunk) {
    return row * 64 + ((chunk ^ (row & 7)) << 3);
}

// HBM -> LDS direct DMA, 16 B per lane. lds ptr must be wave-uniform
// (HW writes base + lane*16); global ptr is per-lane.
__device__ inline void gl_lds16(const ushort_t* g, ushort_t* l) {
    __builtin_amdgcn_global_load_lds(
        (const __attribute__((address_space(1))) unsigned*)g,
        (__attribute__((address_space(3))) unsigned*)l, 16, 0, 0);
}

// ---------------------------------------------------------------------------
// prep: blocks [0,2560) cast x->xb + pos->posb (row 2047 zeroed);
//       blocks [2560,2880) transpose+cast the 5 weight matrices into WT.
// (R4-measured form.)
// ---------------------------------------------------------------------------
__global__ __launch_bounds__(256) void prep(
    const float* __restrict__ x, const float* __restrict__ pos,
    const float* __restrict__ W0, const float* __restrict__ W1,
    const float* __restrict__ W2, const float* __restrict__ W3,
    const float* __restrict__ W4,
    ushort_t* __restrict__ xb, ushort_t* __restrict__ posb,
    ushort_t* __restrict__ WT)
{
    __shared__ float T[64][68];
    const int bx = blockIdx.x;
    const int tid = threadIdx.x;
    if (bx < 2560) {
        const size_t N1 = (size_t)8192 * 512;
        size_t e = ((size_t)bx * 256 + tid) * 8;
        ushort_t tmp[8];
        if (e < N1) {
            const float4* s = (const float4*)(x + e);
            cvt4(s[0], tmp); cvt4(s[1], tmp + 4);
            *(s16x8*)(xb + e) = pack8(tmp);
        } else {
            size_t e2 = e - N1;                 // < 2048*512
            int row = (int)(e2 >> 9);
            if (row < 2047) {
                const float4* s = (const float4*)(pos + e2);
                cvt4(s[0], tmp); cvt4(s[1], tmp + 4);
            } else {
                #pragma unroll
                for (int i = 0; i < 8; ++i) tmp[i] = 0;
            }
            *(s16x8*)(posb + e2) = pack8(tmp);
        }
    } else {
        const int bz = bx - 2560;               // 0..319
        const int z = bz >> 6;                  // 0..4
        const int rem = bz & 63;
        const int n0 = (rem & 7) * 64, k0 = (rem >> 3) * 64;
        const float* W = (z == 0) ? W0 : (z == 1) ? W1
                       : (z == 2) ? W2 : (z == 3) ? W3 : W4;
        const int rr = tid >> 2, cc = (tid & 3) * 16;

        const float* src = W + (size_t)(k0 + rr) * 512 + n0 + cc;
        *(float4*)&T[rr][cc + 0]  = *(const float4*)(src);
        *(float4*)&T[rr][cc + 4]  = *(const float4*)(src + 4);
        *(float4*)&T[rr][cc + 8]  = *(const float4*)(src + 8);
        *(float4*)&T[rr][cc + 12] = *(const float4*)(src + 12);
        __syncthreads();

        ushort_t tmp[16];
        #pragma unroll
        for (int e = 0; e < 16; ++e) tmp[e] = f2bf(T[cc + e][rr]);
        ushort_t* dst = WT + ((size_t)z * 512 + n0 + rr) * 512 + k0 + cc;
        *(s16x8*)dst       = pack8(tmp);
        *(s16x8*)(dst + 8) = pack8(tmp + 8);
    }
}

// ---------------------------------------------------------------------------
// Fused QKV + P GEMM, 128x128 tiles, 4 waves, K=512. (R4-measured form.)
// Double-buffered global_load_lds pipeline: ONE barrier per K-step.
// 1D grid 832 with bijective XCD swizzle (832 = 8*104).
// ---------------------------------------------------------------------------
__global__ __launch_bounds__(256) void gemm_qkvp(
    const ushort_t* __restrict__ xb, const ushort_t* __restrict__ posb,
    const ushort_t* __restrict__ WT,
    const float* __restrict__ bq, const float* __restrict__ bk,
    const float* __restrict__ bv, const float* __restrict__ pbu,
    ushort_t* __restrict__ Qu, ushort_t* __restrict__ Ko,
    ushort_t* __restrict__ VoT, ushort_t* __restrict__ Po)
{
    const int tid = threadIdx.x;
    const int flat = blockIdx.x;                  // 0..831
    const int nf = (flat & 7) * 104 + (flat >> 3);
    const int bxi = nf % 13, byi = nf / 13;

    const bool is_p = (bxi == 12);
    int row0, col0;
    const ushort_t* A;
    const ushort_t* B;
    if (is_p) {
        row0 = (byi >> 2) * 128;                 // 0..1920
        col0 = (byi & 3) * 128;                  // 0..384
        A = posb;
        B = WT + (size_t)3 * 512 * 512;
    } else {
        row0 = byi * 128;
        col0 = bxi * 128;
        A = xb;
        B = WT;                                  // col0 spans 0..1535 across sets
    }
    const int w = tid >> 6, lane = tid & 63;
    const int quad = lane >> 4, lanelo = lane & 15;
    const int wr = w >> 1, wc = w & 1;

    __shared__ ushort_t AsF[2][128 * 64];        // 32 KB (DMA dest, unpadded)
    __shared__ ushort_t BsF[2][128 * 64];        // 32 KB

    const int rs = tid >> 3, js = (tid & 7) * 8;
    const size_t lofs = (size_t)(tid & ~63) * 8; // wave-uniform LDS offset/256-blk

    f32x4 acc[4][4] = {};

    // prologue: stage K-step 0 into buf 0
    #pragma unroll
    for (int i = 0; i < 4; ++i) {
        gl_lds16(A + (size_t)(row0 + i * 32 + rs) * 512 + js,
                 AsF[0] + (size_t)i * 2048 + lofs);
        gl_lds16(B + (size_t)(col0 + i * 32 + rs) * 512 + js,
                 BsF[0] + (size_t)i * 2048 + lofs);
    }

    for (int kk = 0; kk < 8; ++kk) {
        const int cur = kk & 1;
        __syncthreads();                         // drains vmcnt: tile kk visible
        if (kk < 7) {                            // issue DMA for tile kk+1
            const int k1 = (kk + 1) * 64;
            #pragma unroll
            for (int i = 0; i < 4; ++i) {
                gl_lds16(A + (size_t)(row0 + i * 32 + rs) * 512 + k1 + js,
                         AsF[cur ^ 1] + (size_t)i * 2048 + lofs);
                gl_lds16(B + (size_t)(col0 + i * 32 + rs) * 512 + k1 + js,
                         BsF[cur ^ 1] + (size_t)i * 2048 + lofs);
            }
        }
        const ushort_t* Ac = AsF[cur];
        const ushort_t* Bc = BsF[cur];
        #pragma unroll
        for (int ks = 0; ks < 2; ++ks) {
            s16x8 af[4], bf[4];
            #pragma unroll
            for (int i = 0; i < 4; ++i)
                af[i] = *(const s16x8*)(Ac + (size_t)(64 * wr + 16 * i + lanelo) * 64 + ks * 32 + quad * 8);
            #pragma unroll
            for (int j = 0; j < 4; ++j)
                bf[j] = *(const s16x8*)(Bc + (size_t)(64 * wc + 16 * j + lanelo) * 64 + ks * 32 + quad * 8);
            #pragma unroll
            for (int i = 0; i < 4; ++i)
                #pragma unroll
                for (int j = 0; j < 4; ++j)
                    acc[i][j] = mfma16(af[i], bf[j], acc[i][j]);
        }
    }

    if (is_p) {
        #pragma unroll
        for (int j = 0; j < 4; ++j) {
            int c = col0 + 64 * wc + 16 * j + lanelo;
            #pragma unroll
            for (int i = 0; i < 4; ++i)
                #pragma unroll
                for (int r = 0; r < 4; ++r) {
                    int row = row0 + 64 * wr + 16 * i + 4 * quad + r;
                    Po[(size_t)row * 512 + c] = f2bf(acc[i][j][r]);
                }
        }
        return;
    }

    const int set = col0 >> 9;               // 0=Q,1=K,2=V (tile never straddles)
    const int cbase = (col0 & 511) + 64 * wc;
    if (set == 0) {
        #pragma unroll
        for (int j = 0; j < 4; ++j) {
            int c = cbase + 16 * j + lanelo;
            float vq = bq[c] + pbu[c];
            #pragma unroll
            for (int i = 0; i < 4; ++i)
                #pragma unroll
                for (int r = 0; r < 4; ++r) {
                    int row = row0 + 64 * wr + 16 * i + 4 * quad + r;
                    Qu[(size_t)row * 512 + c] = f2bf((acc[i][j][r] + vq) * KSCALE);
                }
        }
    } else if (set == 1) {
        #pragma unroll
        for (int j = 0; j < 4; ++j) {
            int c = cbase + 16 * j + lanelo;
            float vbk = bk[c];
            #pragma unroll
            for (int i = 0; i < 4; ++i)
                #pragma unroll
                for (int r = 0; r < 4; ++r) {
                    int row = row0 + 64 * wr + 16 * i + 4 * quad + r;
                    Ko[(size_t)row * 512 + c] = f2bf(acc[i][j][r] + vbk);
                }
        }
    } else {
        const int b_idx = row0 >> 10;
        #pragma unroll
        for (int j = 0; j < 4; ++j) {
            int c = cbase + 16 * j + lanelo;
            int hh = c >> 6, d = c & 63;
            float vbb = bv[c];
            #pragma unroll
            for (int i = 0; i < 4; ++i) {
                int t = (row0 & 1023) + 64 * wr + 16 * i + 4 * quad;
                ushort4 vp;
                vp.x = f2bf(acc[i][j][0] + vbb);
                vp.y = f2bf(acc[i][j][1] + vbb);
                vp.z = f2bf(acc[i][j][2] + vbb);
                vp.w = f2bf(acc[i][j][3] + vbb);
                *(ushort4*)(VoT + ((size_t)((b_idx * 8 + hh) * 64 + d)) * 1024 + t) = vp;
            }
        }
    }
}

// ===========================================================================
// attn building blocks (always_inline, static indexing only; 128-thread blk)
// ===========================================================================
__device__ __forceinline__ void stage_k64(
    const ushort_t* Kbh, ushort_t* Kd, int sn, int tid)
{
    #pragma unroll
    for (int i = 0; i < 4; ++i) {
        const int L = i * 128 + tid;            // 16B-chunk id, 0..511
        const int r = L >> 3;
        const int ch = (L & 7) ^ (r & 7);       // inverse-swizzled source
        gl_lds16(Kbh + (size_t)(sn + r) * 512 + ch * 8,
                 Kd + (size_t)(i * 128 + (tid & ~63)) * 8);
    }
}
__device__ __forceinline__ void stage_v64(
    const ushort_t* VTbh, ushort_t* Vd, int sn, int tid)
{
    #pragma unroll
    for (int i = 0; i < 4; ++i) {
        const int L = i * 128 + tid;
        const int r = L >> 3;
        const int ch = (L & 7) ^ (r & 7);
        gl_lds16(VTbh + (size_t)r * 1024 + sn + ch * 8,
                 Vd + (size_t)(i * 128 + (tid & ~63)) * 8);
    }
}

// one attention iteration (64 s-cols). pfc = this iter's P frags (registers),
// pfn = next iter's (loaded here, after score, when pfc is dead).
__device__ __forceinline__ void attn_body64(
    int it, bool more,
    const ushort_t* Kc, ushort_t* Kn,
    const ushort_t* Vc, ushort_t* Vn,
    const s16x8 (&pfc)[2][6], s16x8 (&pfn)[2][6],
    const ushort_t* Kbh, const ushort_t* VTbh, const ushort_t* Pfl,
    ushort_t* Ps,
    const s16x8 (&qu0)[2], const s16x8 (&qu1)[2],
    const s16x8 (&qv0)[2], const s16x8 (&qv1)[2],
    f32x4 (&acc_o)[2][4], float (&l_part)[2][4],
    int tid, int w, int quad, int lanelo)
{
    // stage K/V(it+1) into the idle buffers (drains at end barrier)
    if (more) {
        stage_k64(Kbh, Kn, (it + 1) * 64, tid);
        stage_v64(VTbh, Vn, (it + 1) * 64, tid);
    }

    // ---- scores: content (qu.K from LDS) + pos band (qv.P from registers) ----
    f32x4 acc_c[2][4] = {};
    f32x4 acc_g[2][5] = {};
    __builtin_amdgcn_s_setprio(1);
    #pragma unroll
    for (int ks = 0; ks < 2; ++ks) {
        #pragma unroll
        for (int tn = 0; tn < 4; ++tn) {
            s16x8 kf = *(const s16x8*)(Kc + lidx(tn * 16 + lanelo, 4 * ks + quad));
            acc_c[0][tn] = mfma16(qu0[ks], kf, acc_c[0][tn]);
            acc_c[1][tn] = mfma16(qu1[ks], kf, acc_c[1][tn]);
        }
        #pragma unroll
        for (int m = 0; m < 6; ++m) {            // loaded tile = (2-2w)+m
            s16x8 pf = pfc[ks][m];
            if (m >= 1) acc_g[0][m - 1] = mfma16(qv0[ks], pf, acc_g[0][m - 1]);
            if (m <= 4) acc_g[1][m]     = mfma16(qv1[ks], pf, acc_g[1][m]);
        }
    }
    __builtin_amdgcn_s_setprio(0);

    // ---- prefetch P(it+1) (pfc dead now; a full extraction+PV covers latency)
    if (more) {
        const ushort_t* Pn = Pfl + (size_t)(it + 1) * 64 * 512;
        #pragma unroll
        for (int ks = 0; ks < 2; ++ks)
            #pragma unroll
            for (int m = 0; m < 6; ++m)
                pfn[ks][m] = *(const s16x8*)(Pn + (size_t)(16 * m) * 512 + ks * 32);
    }

    // ---- band extraction + exp2 (no max; softmax shift-invariant) ----
    #pragma unroll
    for (int rt = 0; rt < 2; ++rt) {
        #pragma unroll
        for (int r = 0; r < 4; ++r) {
            const int u = lanelo + 15 - 4 * quad - r;   // 0..30
            const int srcl = (quad << 4) | (u & 15);
            const bool hi = (u >= 16);
            float sv[5];
            #pragma unroll
            for (int m = 0; m < 5; ++m) sv[m] = __shfl(acc_g[rt][m][r], srcl);
            #pragma unroll
            for (int tn = 0; tn < 4; ++tn) {
                float e = __builtin_amdgcn_exp2f(acc_c[rt][tn][r] + (hi ? sv[tn + 1] : sv[tn]));
                l_part[rt][r] += e;
                const int pr = 32 * w + 16 * rt + 4 * quad + r;
                const int ch = 2 * tn + (lanelo >> 3);
                Ps[pr * 64 + ((ch ^ (pr & 7)) << 3) + (lanelo & 7)] = f2bf(e);
            }
        }
    }
    asm volatile("s_waitcnt lgkmcnt(0)" ::: "memory");

    // ---- PV: A = probs (wave-private Ps rows), B = V^T tile in LDS ----
    __builtin_amdgcn_s_setprio(1);
    #pragma unroll
    for (int ks = 0; ks < 2; ++ks) {
        s16x8 af0 = *(const s16x8*)(Ps + lidx(32 * w + lanelo, 4 * ks + quad));
        s16x8 af1 = *(const s16x8*)(Ps + lidx(32 * w + 16 + lanelo, 4 * ks + quad));
        #pragma unroll
        for (int dt = 0; dt < 4; ++dt) {
            s16x8 vb = *(const s16x8*)(Vc + lidx(dt * 16 + lanelo, 4 * ks + quad));
            acc_o[0][dt] = mfma16(af0, vb, acc_o[0][dt]);
            acc_o[1][dt] = mfma16(af1, vb, acc_o[1][dt]);
        }
    }
    __builtin_amdgcn_s_setprio(0);

    __syncthreads();   // 2-wave barrier: K/V reads done + staged DMA drained
}

// ---------------------------------------------------------------------------
// MFMA flash attention, decoupled-block variant:
//   block = 64 q-rows, 2 waves x 32 rows. LDS 40 KB (Kt/Vt dbuf + Ps) ->
//   4 blocks/CU; barriers couple only 2 waves; 4 independent blocks drift.
//   P band frags are read DIRECTLY from global (L2-resident, 64B-coalesced
//   per row -- addressing proven in R5) and register-prefetched one full
//   iteration ahead (pfA/pfB, even/odd bodies, static indexing).
//   K/V keep the proven dbuf global_load_lds pipeline, ONE barrier/iter.
//   Grid 1024, XCD swizzle: one b per XCD. launch_bounds(128,2) -> <=256 VGPR.
// ---------------------------------------------------------------------------
__global__ __launch_bounds__(128, 2) void attn_mfma(
    const ushort_t* __restrict__ Qu,
    const ushort_t* __restrict__ Kb, const ushort_t* __restrict__ VT,
    const ushort_t* __restrict__ Pb,
    const float* __restrict__ pbu, const float* __restrict__ pbv,
    ushort_t* __restrict__ AOb)
{
    const int tid = threadIdx.x;                  // 0..127
    const int flat = blockIdx.x;                  // 0..1023
    const int nf = (flat & 7) * 128 + (flat >> 3);// bijective: 1024 = 8*128
    const int t0 = (nf & 15) * 64;
    const int h  = (nf >> 4) & 7;
    const int b  = nf >> 7;

    const int w = tid >> 6, lane = tid & 63;
    const int quad = lane >> 4, lanelo = lane & 15;

    __shared__ ushort_t Kt[2 * 64 * 64];      // 16 KB  [s][d] swizzled, dbuf
    __shared__ ushort_t VtT[2 * 64 * 64];     // 16 KB  [d][s] swizzled, dbuf
    __shared__ ushort_t Ps[64 * 64];          //  8 KB  probs / O staging

    // Q for this wave's 32 rows (2 row-tiles of 16)
    const size_t qr0 = (size_t)(b * T_SEQ + t0 + 32 * w + lanelo) * 512 + h * 64;
    s16x8 qu0[2], qu1[2], qv0[2], qv1[2];
    qu0[0] = *(const s16x8*)(Qu + qr0 + quad * 8);
    qu0[1] = *(const s16x8*)(Qu + qr0 + 32 + quad * 8);
    qu1[0] = *(const s16x8*)(Qu + qr0 + (size_t)16 * 512 + quad * 8);
    qu1[1] = *(const s16x8*)(Qu + qr0 + (size_t)16 * 512 + 32 + quad * 8);
    // qv = qu + (pbv - pbu)*KSCALE  (per-k constant; k = ks*32 + quad*8 + e)
    #pragma unroll
    for (int e = 0; e < 8; ++e) {
        int k0i = h * 64 + quad * 8 + e;
        float d0 = (pbv[k0i] - pbu[k0i]) * KSCALE;
        float d1 = (pbv[k0i + 32] - pbu[k0i + 32]) * KSCALE;
        qv0[0][e] = (short)f2bf(bf2f(qu0[0][e]) + d0);
        qv0[1][e] = (short)f2bf(bf2f(qu0[1][e]) + d1);
        qv1[0][e] = (short)f2bf(bf2f(qu1[0][e]) + d0);
        qv1[1][e] = (short)f2bf(bf2f(qu1[1][e]) + d1);
    }

    f32x4 acc_o[2][4] = {};
    float l_part[2][4] = {{0.f,0.f,0.f,0.f},{0.f,0.f,0.f,0.f}};

    const ushort_t* VTbh = VT + ((size_t)((b * 8 + h) * 64)) * 1024;
    const ushort_t* Kbh  = Kb + (size_t)b * T_SEQ * 512 + (size_t)h * 64;
    const int pr_base = 960 - t0;                 // in [0, 960], mult of 64
    // per-lane P fragment base: row = pr_base + (2-2w)*16 + lanelo (>= 0),
    // frag(it,ks,m) at + (it*64 + 16m)*512 + ks*32. Max row (it=15,w=0,m=5):
    // pr_base + 960 + 112 + 15 <= 2047 ✓ (row 2047 is the zero-pad row).
    const ushort_t* Pfl = Pb + (size_t)(pr_base + (2 - 2 * w) * 16 + lanelo) * 512
                        + h * 64 + quad * 8;

    // ---- prologue: DMA K/V(0) into buf 0; load P(0) frags into pfA ----
    stage_k64(Kbh, Kt, 0, tid);
    stage_v64(VTbh, VtT, 0, tid);
    s16x8 pfA[2][6], pfB[2][6];
    #pragma unroll
    for (int ks = 0; ks < 2; ++ks)
        #pragma unroll
        for (int m = 0; m < 6; ++m)
            pfA[ks][m] = *(const s16x8*)(Pfl + (size_t)(16 * m) * 512 + ks * 32);
    __syncthreads();                              // vmcnt drained by compiler

    for (int it2 = 0; it2 < 8; ++it2) {
        // even body: it = 2*it2, K/V buf0, P frags pfA -> prefetch pfB
        attn_body64(2 * it2, true,
                    Kt, Kt + 4096, VtT, VtT + 4096,
                    pfA, pfB, Kbh, VTbh, Pfl, Ps,
                    qu0, qu1, qv0, qv1, acc_o, l_part,
                    tid, w, quad, lanelo);
        // odd body: it = 2*it2+1, K/V buf1, P frags pfB -> prefetch pfA
        attn_body64(2 * it2 + 1, it2 < 7,
                    Kt + 4096, Kt, VtT + 4096, VtT,
                    pfB, pfA, Kbh, VTbh, Pfl, Ps,
                    qu0, qu1, qv0, qv1, acc_o, l_part,
                    tid, w, quad, lanelo);
    }

    // single end-of-kernel l reduction (16 lanes per row group)
    float inv[2][4];
    #pragma unroll
    for (int rt = 0; rt < 2; ++rt)
        #pragma unroll
        for (int r = 0; r < 4; ++r) {
            float l = l_part[rt][r];
            l += __shfl_xor(l, 1);
            l += __shfl_xor(l, 2);
            l += __shfl_xor(l, 4);
            l += __shfl_xor(l, 8);
            inv[rt][r] = 1.0f / l;
        }

    // epilogue: stage O into Ps (bf16, swizzled), then coalesced vector stores
    #pragma unroll
    for (int rt = 0; rt < 2; ++rt)
        #pragma unroll
        for (int dt = 0; dt < 4; ++dt)
            #pragma unroll
            for (int r = 0; r < 4; ++r) {
                const int pr = 32 * w + 16 * rt + 4 * quad + r;
                const int ch = 2 * dt + (lanelo >> 3);
                Ps[pr * 64 + ((ch ^ (pr & 7)) << 3) + (lanelo & 7)] =
                    f2bf(acc_o[rt][dt][r] * inv[rt][r]);
            }
    __syncthreads();
    {
        const int row = tid >> 1, cb = (tid & 1) * 4;   // 64 rows, 2 thr/row
        ushort_t* dst = AOb + (size_t)(b * T_SEQ + t0 + row) * 512 + h * 64 + cb * 8;
        #pragma unroll
        for (int c = 0; c < 4; ++c)
            *(s16x8*)(dst + c * 8) = *(const s16x8*)(Ps + lidx(row, cb + c));
    }
}

// ---------------------------------------------------------------------------
// Final projection: out = AOb @ WoT + bo  (A bf16, fp32 out), 128x128 tiles,
// double-buffered global_load_lds pipeline (one barrier per K-step).
// 1D grid 256 with XCD swizzle (256 = 8*32).
// ---------------------------------------------------------------------------
__global__ __launch_bounds__(256) void gemm_out(
    const ushort_t* __restrict__ A, const ushort_t* __restrict__ WTo,
    const float* __restrict__ bias, float* __restrict__ C)
{
    const int tid = threadIdx.x;
    const int flat = blockIdx.x;                  // 0..255
    const int nfi = (flat & 7) * 32 + (flat >> 3);
    const int col0 = (nfi & 3) * 128;
    const int row0 = (nfi >> 2) * 128;
    const int w = tid >> 6, lane = tid & 63;
    const int quad = lane >> 4, lanelo = lane & 15;
    const int wr = w >> 1, wc = w & 1;

    __shared__ ushort_t AsF[2][128 * 64];
    __shared__ ushort_t BsF[2][128 * 64];

    const int rs = tid >> 3, js = (tid & 7) * 8;
    const size_t lofs = (size_t)(tid & ~63) * 8;

    f32x4 acc[4][4] = {};

    // prologue: stage K-step 0 into buf 0
    #pragma unroll
    for (int i = 0; i < 4; ++i) {
        gl_lds16(A + (size_t)(row0 + i * 32 + rs) * 512 + js,
                 AsF[0] + (size_t)i * 2048 + lofs);
        gl_lds16(WTo + (size_t)(col0 + i * 32 + rs) * 512 + js,
                 BsF[0] + (size_t)i * 2048 + lofs);
    }

    for (int kk = 0; kk < 8; ++kk) {
        const int cur = kk & 1;
        __syncthreads();
        if (kk < 7) {
            const int k1 = (kk + 1) * 64;
            #pragma unroll
            for (int i = 0; i < 4; ++i) {
                gl_lds16(A + (size_t)(row0 + i * 32 + rs) * 512 + k1 + js,
                         AsF[cur ^ 1] + (size_t)i * 2048 + lofs);
                gl_lds16(WTo + (size_t)(col0 + i * 32 + rs) * 512 + k1 + js,
                         BsF[cur ^ 1] + (size_t)i * 2048 + lofs);
            }
        }
        const ushort_t* Ac = AsF[cur];
        const ushort_t* Bc = BsF[cur];
        #pragma unroll
        for (int ks = 0; ks < 2; ++ks) {
            s16x8 af[4], bf[4];
            #pragma unroll
            for (int i = 0; i < 4; ++i)
                af[i] = *(const s16x8*)(Ac + (size_t)(64 * wr + 16 * i + lanelo) * 64 + ks * 32 + quad * 8);
            #pragma unroll
            for (int j = 0; j < 4; ++j)
                bf[j] = *(const s16x8*)(Bc + (size_t)(64 * wc + 16 * j + lanelo) * 64 + ks * 32 + quad * 8);
            #pragma unroll
            for (int i = 0; i < 4; ++i)
                #pragma unroll
                for (int j = 0; j < 4; ++j)
                    acc[i][j] = mfma16(af[i], bf[j], acc[i][j]);
        }
    }

    #pragma unroll
    for (int j = 0; j < 4; ++j) {
        int c = col0 + 64 * wc + 16 * j + lanelo;
        float vb = bias[c];
        #pragma unroll
        for (int i = 0; i < 4; ++i)
            #pragma unroll
            for (int r = 0; r < 4; ++r) {
                int row = row0 + 64 * wr + 16 * i + 4 * quad + r;
                C[(size_t)row * 512 + c] = acc[i][j][r] + vb;
            }
    }
}

// ---------------------------------------------------------------------------
extern "C" void kernel_launch(void* const* d_in, const int* in_sizes, int n_in,
                              void* d_out, int out_size, void* d_ws, size_t ws_size,
                              hipStream_t stream) {
    const float* x       = (const float*)d_in[0];
    const float* pos_enc = (const float*)d_in[1];
    const float* Wq      = (const float*)d_in[2];
    const float* bq      = (const float*)d_in[3];
    const float* Wk      = (const float*)d_in[4];
    const float* bk      = (const float*)d_in[5];
    const float* Wv      = (const float*)d_in[6];
    const float* bv      = (const float*)d_in[7];
    const float* Wpos    = (const float*)d_in[8];
    const float* pbu     = (const float*)d_in[9];
    const float* pbv     = (const float*)d_in[10];
    const float* Wo      = (const float*)d_in[11];
    const float* bo      = (const float*)d_in[12];
    float* out = (float*)d_out;

    const size_t M  = 8 * T_SEQ;                 // 8192
    const size_t SZ = M * D_MODEL;               // 4,194,304

    char* ws = (char*)d_ws;
    ushort_t* xb   = (ushort_t*)ws;              ws += SZ * 2;
    ushort_t* posb = (ushort_t*)ws;              ws += (size_t)2048 * 512 * 2;
    ushort_t* Qu_b = (ushort_t*)ws;              ws += SZ * 2;
    ushort_t* K_b  = (ushort_t*)ws;              ws += SZ * 2;
    ushort_t* VT_b = (ushort_t*)ws;              ws += SZ * 2;
    ushort_t* P_b  = (ushort_t*)ws;              ws += (size_t)2048 * 512 * 2;
    ushort_t* WT   = (ushort_t*)ws;              ws += (size_t)5 * 512 * 512 * 2;
    ushort_t* AOb  = (ushort_t*)ws;              ws += SZ * 2;

    dim3 blk(256);

    hipLaunchKernelGGL(prep, dim3(2880), blk, 0, stream,
                       x, pos_enc, Wq, Wk, Wv, Wpos, Wo, xb, posb, WT);

    hipLaunchKernelGGL(gemm_qkvp, dim3(832), blk, 0, stream,
                       xb, posb, WT, bq, bk, bv, pbu,
                       Qu_b, K_b, VT_b, P_b);

    hipLaunchKernelGGL(attn_mfma, dim3(1024), dim3(128), 0, stream,
                       Qu_b, K_b, VT_b, P_b, pbu, pbv, AOb);

    hipLaunchKernelGGL(gemm_out, dim3(256), blk, 0, stream,
                       AOb, WT + (size_t)4 * 512 * 512, bo, out);
}

// Round 9
// 225.515 us; speedup vs baseline: 1.6861x; 1.6861x over previous
//
#include <hip/hip_runtime.h>
#include <hip/hip_bf16.h>

#define T_SEQ 1024
#define D_MODEL 512
#define N_HEADS 8
#define D_HEAD 64
// 0.125 (1/sqrt(64)) * log2(e): scores computed directly in exp2 domain
#define KSCALE 0.1803368801111244f

typedef unsigned short ushort_t;
typedef short s16x8 __attribute__((ext_vector_type(8)));
typedef float f32x4 __attribute__((ext_vector_type(4)));

__device__ inline f32x4 mfma16(s16x8 a, s16x8 b, f32x4 c) {
    return __builtin_amdgcn_mfma_f32_16x16x32_bf16(a, b, c, 0, 0, 0);
}

__device__ inline ushort_t f2bf(float f) {   // RTNE float->bf16
    union { float f; unsigned u; } v; v.f = f;
    unsigned r = v.u + 0x7FFFu + ((v.u >> 16) & 1u);
    return (ushort_t)(r >> 16);
}
__device__ inline float bf2f(short s) {
    union { unsigned u; float f; } t; t.u = ((unsigned)(unsigned short)s) << 16; return t.f;
}
__device__ inline void cvt4(const float4 f, ushort_t* t) {
    t[0] = f2bf(f.x); t[1] = f2bf(f.y); t[2] = f2bf(f.z); t[3] = f2bf(f.w);
}
__device__ inline s16x8 pack8(const ushort_t* t) {
    s16x8 r;
    #pragma unroll
    for (int e = 0; e < 8; ++e) r[e] = (short)t[e];
    return r;
}

// XOR-swizzled LDS index for 64-u16-wide buffers: 16B chunk ^= (row & 7).
// Frag reads (chunk = 4ks+quad, row%8 = lanelo%8) become bank-conflict-free.
// Involution: physical chunk = logical chunk ^ (row&7) on BOTH write and read.
__device__ inline int lidx(int row, int chunk) {
    return row * 64 + ((chunk ^ (row & 7)) << 3);
}

// HBM -> LDS direct DMA, 16 B per lane. lds ptr must be wave-uniform
// (HW writes base + lane*16); global ptr is per-lane.
__device__ inline void gl_lds16(const ushort_t* g, ushort_t* l) {
    __builtin_amdgcn_global_load_lds(
        (const __attribute__((address_space(1))) unsigned*)g,
        (__attribute__((address_space(3))) unsigned*)l, 16, 0, 0);
}

// ---------------------------------------------------------------------------
// prep: blocks [0,2560) cast x->xb + pos->posb (row 2047 zeroed);
//       blocks [2560,2880) transpose+cast the 5 weight matrices into WT.
// (R4-measured form.)
// ---------------------------------------------------------------------------
__global__ __launch_bounds__(256) void prep(
    const float* __restrict__ x, const float* __restrict__ pos,
    const float* __restrict__ W0, const float* __restrict__ W1,
    const float* __restrict__ W2, const float* __restrict__ W3,
    const float* __restrict__ W4,
    ushort_t* __restrict__ xb, ushort_t* __restrict__ posb,
    ushort_t* __restrict__ WT)
{
    __shared__ float T[64][68];
    const int bx = blockIdx.x;
    const int tid = threadIdx.x;
    if (bx < 2560) {
        const size_t N1 = (size_t)8192 * 512;
        size_t e = ((size_t)bx * 256 + tid) * 8;
        ushort_t tmp[8];
        if (e < N1) {
            const float4* s = (const float4*)(x + e);
            cvt4(s[0], tmp); cvt4(s[1], tmp + 4);
            *(s16x8*)(xb + e) = pack8(tmp);
        } else {
            size_t e2 = e - N1;                 // < 2048*512
            int row = (int)(e2 >> 9);
            if (row < 2047) {
                const float4* s = (const float4*)(pos + e2);
                cvt4(s[0], tmp); cvt4(s[1], tmp + 4);
            } else {
                #pragma unroll
                for (int i = 0; i < 8; ++i) tmp[i] = 0;
            }
            *(s16x8*)(posb + e2) = pack8(tmp);
        }
    } else {
        const int bz = bx - 2560;               // 0..319
        const int z = bz >> 6;                  // 0..4
        const int rem = bz & 63;
        const int n0 = (rem & 7) * 64, k0 = (rem >> 3) * 64;
        const float* W = (z == 0) ? W0 : (z == 1) ? W1
                       : (z == 2) ? W2 : (z == 3) ? W3 : W4;
        const int rr = tid >> 2, cc = (tid & 3) * 16;

        const float* src = W + (size_t)(k0 + rr) * 512 + n0 + cc;
        *(float4*)&T[rr][cc + 0]  = *(const float4*)(src);
        *(float4*)&T[rr][cc + 4]  = *(const float4*)(src + 4);
        *(float4*)&T[rr][cc + 8]  = *(const float4*)(src + 8);
        *(float4*)&T[rr][cc + 12] = *(const float4*)(src + 12);
        __syncthreads();

        ushort_t tmp[16];
        #pragma unroll
        for (int e = 0; e < 16; ++e) tmp[e] = f2bf(T[cc + e][rr]);
        ushort_t* dst = WT + ((size_t)z * 512 + n0 + rr) * 512 + k0 + cc;
        *(s16x8*)dst       = pack8(tmp);
        *(s16x8*)(dst + 8) = pack8(tmp + 8);
    }
}

// ---------------------------------------------------------------------------
// Fused QKV + P GEMM, 128x128 tiles, 4 waves, K=512. (R4-measured form.)
// Double-buffered global_load_lds pipeline: ONE barrier per K-step.
// 1D grid 832 with bijective XCD swizzle (832 = 8*104).
// ---------------------------------------------------------------------------
__global__ __launch_bounds__(256) void gemm_qkvp(
    const ushort_t* __restrict__ xb, const ushort_t* __restrict__ posb,
    const ushort_t* __restrict__ WT,
    const float* __restrict__ bq, const float* __restrict__ bk,
    const float* __restrict__ bv, const float* __restrict__ pbu,
    ushort_t* __restrict__ Qu, ushort_t* __restrict__ Ko,
    ushort_t* __restrict__ VoT, ushort_t* __restrict__ Po)
{
    const int tid = threadIdx.x;
    const int flat = blockIdx.x;                  // 0..831
    const int nf = (flat & 7) * 104 + (flat >> 3);
    const int bxi = nf % 13, byi = nf / 13;

    const bool is_p = (bxi == 12);
    int row0, col0;
    const ushort_t* A;
    const ushort_t* B;
    if (is_p) {
        row0 = (byi >> 2) * 128;                 // 0..1920
        col0 = (byi & 3) * 128;                  // 0..384
        A = posb;
        B = WT + (size_t)3 * 512 * 512;
    } else {
        row0 = byi * 128;
        col0 = bxi * 128;
        A = xb;
        B = WT;                                  // col0 spans 0..1535 across sets
    }
    const int w = tid >> 6, lane = tid & 63;
    const int quad = lane >> 4, lanelo = lane & 15;
    const int wr = w >> 1, wc = w & 1;

    __shared__ ushort_t AsF[2][128 * 64];        // 32 KB (DMA dest, unpadded)
    __shared__ ushort_t BsF[2][128 * 64];        // 32 KB

    const int rs = tid >> 3, js = (tid & 7) * 8;
    const size_t lofs = (size_t)(tid & ~63) * 8; // wave-uniform LDS offset/256-blk

    f32x4 acc[4][4] = {};

    // prologue: stage K-step 0 into buf 0
    #pragma unroll
    for (int i = 0; i < 4; ++i) {
        gl_lds16(A + (size_t)(row0 + i * 32 + rs) * 512 + js,
                 AsF[0] + (size_t)i * 2048 + lofs);
        gl_lds16(B + (size_t)(col0 + i * 32 + rs) * 512 + js,
                 BsF[0] + (size_t)i * 2048 + lofs);
    }

    for (int kk = 0; kk < 8; ++kk) {
        const int cur = kk & 1;
        __syncthreads();                         // drains vmcnt: tile kk visible
        if (kk < 7) {                            // issue DMA for tile kk+1
            const int k1 = (kk + 1) * 64;
            #pragma unroll
            for (int i = 0; i < 4; ++i) {
                gl_lds16(A + (size_t)(row0 + i * 32 + rs) * 512 + k1 + js,
                         AsF[cur ^ 1] + (size_t)i * 2048 + lofs);
                gl_lds16(B + (size_t)(col0 + i * 32 + rs) * 512 + k1 + js,
                         BsF[cur ^ 1] + (size_t)i * 2048 + lofs);
            }
        }
        const ushort_t* Ac = AsF[cur];
        const ushort_t* Bc = BsF[cur];
        #pragma unroll
        for (int ks = 0; ks < 2; ++ks) {
            s16x8 af[4], bf[4];
            #pragma unroll
            for (int i = 0; i < 4; ++i)
                af[i] = *(const s16x8*)(Ac + (size_t)(64 * wr + 16 * i + lanelo) * 64 + ks * 32 + quad * 8);
            #pragma unroll
            for (int j = 0; j < 4; ++j)
                bf[j] = *(const s16x8*)(Bc + (size_t)(64 * wc + 16 * j + lanelo) * 64 + ks * 32 + quad * 8);
            #pragma unroll
            for (int i = 0; i < 4; ++i)
                #pragma unroll
                for (int j = 0; j < 4; ++j)
                    acc[i][j] = mfma16(af[i], bf[j], acc[i][j]);
        }
    }

    if (is_p) {
        #pragma unroll
        for (int j = 0; j < 4; ++j) {
            int c = col0 + 64 * wc + 16 * j + lanelo;
            #pragma unroll
            for (int i = 0; i < 4; ++i)
                #pragma unroll
                for (int r = 0; r < 4; ++r) {
                    int row = row0 + 64 * wr + 16 * i + 4 * quad + r;
                    Po[(size_t)row * 512 + c] = f2bf(acc[i][j][r]);
                }
        }
        return;
    }

    const int set = col0 >> 9;               // 0=Q,1=K,2=V (tile never straddles)
    const int cbase = (col0 & 511) + 64 * wc;
    if (set == 0) {
        #pragma unroll
        for (int j = 0; j < 4; ++j) {
            int c = cbase + 16 * j + lanelo;
            float vq = bq[c] + pbu[c];
            #pragma unroll
            for (int i = 0; i < 4; ++i)
                #pragma unroll
                for (int r = 0; r < 4; ++r) {
                    int row = row0 + 64 * wr + 16 * i + 4 * quad + r;
                    Qu[(size_t)row * 512 + c] = f2bf((acc[i][j][r] + vq) * KSCALE);
                }
        }
    } else if (set == 1) {
        #pragma unroll
        for (int j = 0; j < 4; ++j) {
            int c = cbase + 16 * j + lanelo;
            float vbk = bk[c];
            #pragma unroll
            for (int i = 0; i < 4; ++i)
                #pragma unroll
                for (int r = 0; r < 4; ++r) {
                    int row = row0 + 64 * wr + 16 * i + 4 * quad + r;
                    Ko[(size_t)row * 512 + c] = f2bf(acc[i][j][r] + vbk);
                }
        }
    } else {
        const int b_idx = row0 >> 10;
        #pragma unroll
        for (int j = 0; j < 4; ++j) {
            int c = cbase + 16 * j + lanelo;
            int hh = c >> 6, d = c & 63;
            float vbb = bv[c];
            #pragma unroll
            for (int i = 0; i < 4; ++i) {
                int t = (row0 & 1023) + 64 * wr + 16 * i + 4 * quad;
                ushort4 vp;
                vp.x = f2bf(acc[i][j][0] + vbb);
                vp.y = f2bf(acc[i][j][1] + vbb);
                vp.z = f2bf(acc[i][j][2] + vbb);
                vp.w = f2bf(acc[i][j][3] + vbb);
                *(ushort4*)(VoT + ((size_t)((b_idx * 8 + hh) * 64 + d)) * 1024 + t) = vp;
            }
        }
    }
}

// ---------------------------------------------------------------------------
// MFMA flash attention (R4-measured structure, + shuffle-dedup extraction):
//   block = 128 q-rows, 4 waves x 32 rows (2 row-tiles of 16 per wave).
//   K/V double-buffered + 256-slot circular P window -> ONE barrier/iter.
//   All staging via global_load_lds with pre-swizzled SOURCE. Grid 512, XCD
//   swizzle (one b per XCD). LDS 80 KB -> 2 blocks/CU; ~124 VGPR.
//   Extraction: sv[m] hoists the 5 distinct acc_g shuffles per (rt,r)
//   (was 8 with the v0/v1 pair form; v1(tn) == v0(tn+1)) -> 40 vs 64
//   shuffles/iter, register-neutral, bit-identical values.
// ---------------------------------------------------------------------------
__global__ __launch_bounds__(256, 2) void attn_mfma(
    const ushort_t* __restrict__ Qu,
    const ushort_t* __restrict__ Kb, const ushort_t* __restrict__ VT,
    const ushort_t* __restrict__ Pb,
    const float* __restrict__ pbu, const float* __restrict__ pbv,
    ushort_t* __restrict__ AOb)
{
    const int tid = threadIdx.x;
    const int flat = blockIdx.x;                  // 0..511
    const int nf = (flat & 7) * 64 + (flat >> 3); // bijective: 512 = 8*64
    const int t0 = (nf & 7) * 128;
    const int h  = (nf >> 3) & 7;
    const int b  = nf >> 6;

    const int w = tid >> 6, lane = tid & 63;
    const int quad = lane >> 4, lanelo = lane & 15;

    __shared__ ushort_t Kt[2 * 64 * 64];      // 16 KB  [s][d] swizzled, dbuf
    __shared__ ushort_t VtT[2 * 64 * 64];     // 16 KB  [d][s] swizzled, dbuf
    __shared__ ushort_t Pt[256 * 64];         // 32 KB  circular window, swizzled
    __shared__ ushort_t Ps[128 * 64];         // 16 KB  probs / O staging

    // Q for this wave's 32 rows (2 row-tiles of 16)
    const size_t qr0 = (size_t)(b * T_SEQ + t0 + 32 * w + lanelo) * 512 + h * 64;
    s16x8 qu0[2], qu1[2], qv0[2], qv1[2];
    qu0[0] = *(const s16x8*)(Qu + qr0 + quad * 8);
    qu0[1] = *(const s16x8*)(Qu + qr0 + 32 + quad * 8);
    qu1[0] = *(const s16x8*)(Qu + qr0 + (size_t)16 * 512 + quad * 8);
    qu1[1] = *(const s16x8*)(Qu + qr0 + (size_t)16 * 512 + 32 + quad * 8);
    // qv = qu + (pbv - pbu)*KSCALE  (per-k constant; k = ks*32 + quad*8 + e)
    #pragma unroll
    for (int e = 0; e < 8; ++e) {
        int k0i = h * 64 + quad * 8 + e;
        float d0 = (pbv[k0i] - pbu[k0i]) * KSCALE;
        float d1 = (pbv[k0i + 32] - pbu[k0i + 32]) * KSCALE;
        qv0[0][e] = (short)f2bf(bf2f(qu0[0][e]) + d0);
        qv0[1][e] = (short)f2bf(bf2f(qu0[1][e]) + d1);
        qv1[0][e] = (short)f2bf(bf2f(qu1[0][e]) + d0);
        qv1[1][e] = (short)f2bf(bf2f(qu1[1][e]) + d1);
    }

    f32x4 acc_o[2][4] = {};
    float l_part[2][4] = {{0.f,0.f,0.f,0.f},{0.f,0.f,0.f,0.f}};

    const ushort_t* VTbh = VT + ((size_t)((b * 8 + h) * 64)) * 1024;
    const ushort_t* Kbh  = Kb + (size_t)b * T_SEQ * 512 + (size_t)h * 64;
    const int pr_base = 960 - t0;               // in [64, 960], mult of 64

    // ---- prologue: DMA iter-0 K/V (buf 0) + 192-row P window ----
    {
        #pragma unroll
        for (int i = 0; i < 2; ++i) {
            const int L = i * 256 + tid;
            const int r = L >> 3;
            const int ch = (L & 7) ^ (r & 7);    // inverse-swizzled source
            gl_lds16(Kbh + (size_t)r * 512 + ch * 8,
                     Kt + (size_t)(i * 256 + (tid & ~63)) * 8);
            gl_lds16(VTbh + (size_t)r * 1024 + ch * 8,
                     VtT + (size_t)(i * 256 + (tid & ~63)) * 8);
        }
        const int g0p = pr_base - 64;            // >= 0, mult of 64
        #pragma unroll
        for (int i = 0; i < 6; ++i) {
            const int L = i * 256 + tid;
            const int gr = g0p + (L >> 3);
            const int ch = (L & 7) ^ (gr & 7);
            const int sgb = (g0p + ((i * 256 + (tid & ~63)) >> 3)) & 255; // wave-uniform
            gl_lds16(Pb + (size_t)gr * 512 + h * 64 + ch * 8,
                     Pt + (size_t)sgb * 64);
        }
    }
    __syncthreads();                             // vmcnt drained by compiler

    for (int it = 0; it < 16; ++it) {
        const int s0 = it * 64;
        const int cur = it & 1;

        // ---- issue next-tile DMA into idle buffers (drains at end barrier,
        //      latency covered by this iteration's compute) ----
        if (it < 15) {
            ushort_t* Kn = Kt + (cur ^ 1) * 4096;
            ushort_t* Vn = VtT + (cur ^ 1) * 4096;
            const int sn = s0 + 64;
            #pragma unroll
            for (int i = 0; i < 2; ++i) {
                const int L = i * 256 + tid;
                const int r = L >> 3;
                const int ch = (L & 7) ^ (r & 7);
                gl_lds16(Kbh + (size_t)(sn + r) * 512 + ch * 8,
                         Kn + (size_t)(i * 256 + (tid & ~63)) * 8);
                gl_lds16(VTbh + (size_t)r * 1024 + sn + ch * 8,
                         Vn + (size_t)(i * 256 + (tid & ~63)) * 8);
            }
            const int g0 = pr_base + s0 + 128;   // rows g0..g0+63 (max 2047)
            #pragma unroll
            for (int i = 0; i < 2; ++i) {
                const int L = i * 256 + tid;
                const int gr = g0 + (L >> 3);
                const int ch = (L & 7) ^ (gr & 7);
                const int sgb = (g0 + ((i * 256 + (tid & ~63)) >> 3)) & 255;
                gl_lds16(Pb + (size_t)gr * 512 + h * 64 + ch * 8,
                         Pt + (size_t)sgb * 64);
            }
        }

        const ushort_t* Kc = Kt + cur * 4096;
        const ushort_t* Vc = VtT + cur * 4096;
        const int pb = (pr_base + s0) & 255;     // window base slot

        // ---- scores: content (8 MFMA/ks) + pos band (10 MFMA/ks, 6 loads) ----
        f32x4 acc_c[2][4] = {};
        f32x4 acc_g[2][5] = {};
        __builtin_amdgcn_s_setprio(1);
        #pragma unroll
        for (int ks = 0; ks < 2; ++ks) {
            #pragma unroll
            for (int tn = 0; tn < 4; ++tn) {
                s16x8 kf = *(const s16x8*)(Kc + lidx(tn * 16 + lanelo, 4 * ks + quad));
                acc_c[0][tn] = mfma16(qu0[ks], kf, acc_c[0][tn]);
                acc_c[1][tn] = mfma16(qu1[ks], kf, acc_c[1][tn]);
            }
            #pragma unroll
            for (int m = 0; m < 6; ++m) {        // loaded tile = (2-2w)+m
                int prow = (pb + 256 + (2 - 2 * w + m) * 16 + lanelo) & 255;
                s16x8 pf = *(const s16x8*)(Pt + lidx(prow, 4 * ks + quad));
                if (m >= 1) acc_g[0][m - 1] = mfma16(qv0[ks], pf, acc_g[0][m - 1]);
                if (m <= 4) acc_g[1][m]     = mfma16(qv1[ks], pf, acc_g[1][m]);
            }
        }
        __builtin_amdgcn_s_setprio(0);

        // ---- band extraction + exp2 (no max; softmax shift-invariant).
        //      sv[m] dedups the shuffles: v1 of tile tn == v0 of tile tn+1.
        #pragma unroll
        for (int rt = 0; rt < 2; ++rt) {
            #pragma unroll
            for (int r = 0; r < 4; ++r) {
                const int u = lanelo + 15 - 4 * quad - r;   // 0..30
                const int srcl = (quad << 4) | (u & 15);
                const bool hi = (u >= 16);
                float sv[5];
                #pragma unroll
                for (int m = 0; m < 5; ++m) sv[m] = __shfl(acc_g[rt][m][r], srcl);
                #pragma unroll
                for (int tn = 0; tn < 4; ++tn) {
                    float e = __builtin_amdgcn_exp2f(acc_c[rt][tn][r] + (hi ? sv[tn + 1] : sv[tn]));
                    l_part[rt][r] += e;
                    const int pr = 32 * w + 16 * rt + 4 * quad + r;
                    const int ch = 2 * tn + (lanelo >> 3);
                    Ps[pr * 64 + ((ch ^ (pr & 7)) << 3) + (lanelo & 7)] = f2bf(e);
                }
            }
        }
        asm volatile("s_waitcnt lgkmcnt(0)" ::: "memory");

        // ---- PV: A = probs (wave-private Ps rows), B = V^T tile ----
        __builtin_amdgcn_s_setprio(1);
        #pragma unroll
        for (int ks = 0; ks < 2; ++ks) {
            s16x8 af0 = *(const s16x8*)(Ps + lidx(32 * w + lanelo, 4 * ks + quad));
            s16x8 af1 = *(const s16x8*)(Ps + lidx(32 * w + 16 + lanelo, 4 * ks + quad));
            #pragma unroll
            for (int dt = 0; dt < 4; ++dt) {
                s16x8 vb = *(const s16x8*)(Vc + lidx(dt * 16 + lanelo, 4 * ks + quad));
                acc_o[0][dt] = mfma16(af0, vb, acc_o[0][dt]);
                acc_o[1][dt] = mfma16(af1, vb, acc_o[1][dt]);
            }
        }
        __builtin_amdgcn_s_setprio(0);

        __syncthreads();   // single barrier: reads done + staged DMA drained
    }

    // single end-of-kernel l reduction (16 lanes per row group)
    float inv[2][4];
    #pragma unroll
    for (int rt = 0; rt < 2; ++rt)
        #pragma unroll
        for (int r = 0; r < 4; ++r) {
            float l = l_part[rt][r];
            l += __shfl_xor(l, 1);
            l += __shfl_xor(l, 2);
            l += __shfl_xor(l, 4);
            l += __shfl_xor(l, 8);
            inv[rt][r] = 1.0f / l;
        }

    // epilogue: stage O into Ps (bf16, swizzled), then coalesced vector stores
    #pragma unroll
    for (int rt = 0; rt < 2; ++rt)
        #pragma unroll
        for (int dt = 0; dt < 4; ++dt)
            #pragma unroll
            for (int r = 0; r < 4; ++r) {
                const int pr = 32 * w + 16 * rt + 4 * quad + r;
                const int ch = 2 * dt + (lanelo >> 3);
                Ps[pr * 64 + ((ch ^ (pr & 7)) << 3) + (lanelo & 7)] =
                    f2bf(acc_o[rt][dt][r] * inv[rt][r]);
            }
    __syncthreads();
    {
        const int row = tid >> 1, cb = (tid & 1) * 4;
        ushort_t* dst = AOb + (size_t)(b * T_SEQ + t0 + row) * 512 + h * 64 + cb * 8;
        #pragma unroll
        for (int c = 0; c < 4; ++c)
            *(s16x8*)(dst + c * 8) = *(const s16x8*)(Ps + lidx(row, cb + c));
    }
}

// ---------------------------------------------------------------------------
// Final projection: out = AOb @ WoT + bo  (A bf16, fp32 out), 128x128 tiles,
// double-buffered global_load_lds pipeline (one barrier per K-step).
// 1D grid 256 with XCD swizzle (256 = 8*32).
// ---------------------------------------------------------------------------
__global__ __launch_bounds__(256) void gemm_out(
    const ushort_t* __restrict__ A, const ushort_t* __restrict__ WTo,
    const float* __restrict__ bias, float* __restrict__ C)
{
    const int tid = threadIdx.x;
    const int flat = blockIdx.x;                  // 0..255
    const int nfi = (flat & 7) * 32 + (flat >> 3);
    const int col0 = (nfi & 3) * 128;
    const int row0 = (nfi >> 2) * 128;
    const int w = tid >> 6, lane = tid & 63;
    const int quad = lane >> 4, lanelo = lane & 15;
    const int wr = w >> 1, wc = w & 1;

    __shared__ ushort_t AsF[2][128 * 64];
    __shared__ ushort_t BsF[2][128 * 64];

    const int rs = tid >> 3, js = (tid & 7) * 8;
    const size_t lofs = (size_t)(tid & ~63) * 8;

    f32x4 acc[4][4] = {};

    // prologue: stage K-step 0 into buf 0
    #pragma unroll
    for (int i = 0; i < 4; ++i) {
        gl_lds16(A + (size_t)(row0 + i * 32 + rs) * 512 + js,
                 AsF[0] + (size_t)i * 2048 + lofs);
        gl_lds16(WTo + (size_t)(col0 + i * 32 + rs) * 512 + js,
                 BsF[0] + (size_t)i * 2048 + lofs);
    }

    for (int kk = 0; kk < 8; ++kk) {
        const int cur = kk & 1;
        __syncthreads();
        if (kk < 7) {
            const int k1 = (kk + 1) * 64;
            #pragma unroll
            for (int i = 0; i < 4; ++i) {
                gl_lds16(A + (size_t)(row0 + i * 32 + rs) * 512 + k1 + js,
                         AsF[cur ^ 1] + (size_t)i * 2048 + lofs);
                gl_lds16(WTo + (size_t)(col0 + i * 32 + rs) * 512 + k1 + js,
                         BsF[cur ^ 1] + (size_t)i * 2048 + lofs);
            }
        }
        const ushort_t* Ac = AsF[cur];
        const ushort_t* Bc = BsF[cur];
        #pragma unroll
        for (int ks = 0; ks < 2; ++ks) {
            s16x8 af[4], bf[4];
            #pragma unroll
            for (int i = 0; i < 4; ++i)
                af[i] = *(const s16x8*)(Ac + (size_t)(64 * wr + 16 * i + lanelo) * 64 + ks * 32 + quad * 8);
            #pragma unroll
            for (int j = 0; j < 4; ++j)
                bf[j] = *(const s16x8*)(Bc + (size_t)(64 * wc + 16 * j + lanelo) * 64 + ks * 32 + quad * 8);
            #pragma unroll
            for (int i = 0; i < 4; ++i)
                #pragma unroll
                for (int j = 0; j < 4; ++j)
                    acc[i][j] = mfma16(af[i], bf[j], acc[i][j]);
        }
    }

    #pragma unroll
    for (int j = 0; j < 4; ++j) {
        int c = col0 + 64 * wc + 16 * j + lanelo;
        float vb = bias[c];
        #pragma unroll
        for (int i = 0; i < 4; ++i)
            #pragma unroll
            for (int r = 0; r < 4; ++r) {
                int row = row0 + 64 * wr + 16 * i + 4 * quad + r;
                C[(size_t)row * 512 + c] = acc[i][j][r] + vb;
            }
    }
}

// ---------------------------------------------------------------------------
extern "C" void kernel_launch(void* const* d_in, const int* in_sizes, int n_in,
                              void* d_out, int out_size, void* d_ws, size_t ws_size,
                              hipStream_t stream) {
    const float* x       = (const float*)d_in[0];
    const float* pos_enc = (const float*)d_in[1];
    const float* Wq      = (const float*)d_in[2];
    const float* bq      = (const float*)d_in[3];
    const float* Wk      = (const float*)d_in[4];
    const float* bk      = (const float*)d_in[5];
    const float* Wv      = (const float*)d_in[6];
    const float* bv      = (const float*)d_in[7];
    const float* Wpos    = (const float*)d_in[8];
    const float* pbu     = (const float*)d_in[9];
    const float* pbv     = (const float*)d_in[10];
    const float* Wo      = (const float*)d_in[11];
    const float* bo      = (const float*)d_in[12];
    float* out = (float*)d_out;

    const size_t M  = 8 * T_SEQ;                 // 8192
    const size_t SZ = M * D_MODEL;               // 4,194,304

    char* ws = (char*)d_ws;
    ushort_t* xb   = (ushort_t*)ws;              ws += SZ * 2;
    ushort_t* posb = (ushort_t*)ws;              ws += (size_t)2048 * 512 * 2;
    ushort_t* Qu_b = (ushort_t*)ws;              ws += SZ * 2;
    ushort_t* K_b  = (ushort_t*)ws;              ws += SZ * 2;
    ushort_t* VT_b = (ushort_t*)ws;              ws += SZ * 2;
    ushort_t* P_b  = (ushort_t*)ws;              ws += (size_t)2048 * 512 * 2;
    ushort_t* WT   = (ushort_t*)ws;              ws += (size_t)5 * 512 * 512 * 2;
    ushort_t* AOb  = (ushort_t*)ws;              ws += SZ * 2;

    dim3 blk(256);

    hipLaunchKernelGGL(prep, dim3(2880), blk, 0, stream,
                       x, pos_enc, Wq, Wk, Wv, Wpos, Wo, xb, posb, WT);

    hipLaunchKernelGGL(gemm_qkvp, dim3(832), blk, 0, stream,
                       xb, posb, WT, bq, bk, bv, pbu,
                       Qu_b, K_b, VT_b, P_b);

    hipLaunchKernelGGL(attn_mfma, dim3(512), blk, 0, stream,
                       Qu_b, K_b, VT_b, P_b, pbu, pbv, AOb);

    hipLaunchKernelGGL(gemm_out, dim3(256), blk, 0, stream,
                       AOb, WT + (size_t)4 * 512 * 512, bo, out);
}

// Round 10
// 185.792 us; speedup vs baseline: 2.0466x; 1.2138x over previous
//
#include <hip/hip_runtime.h>
#include <hip/hip_bf16.h>

#define T_SEQ 1024
#define D_MODEL 512
#define N_HEADS 8
#define D_HEAD 64
// 0.125 (1/sqrt(64)) * log2(e): scores computed directly in exp2 domain
#define KSCALE 0.1803368801111244f

typedef unsigned short ushort_t;
typedef short s16x8 __attribute__((ext_vector_type(8)));
typedef float f32x4 __attribute__((ext_vector_type(4)));

__device__ inline f32x4 mfma16(s16x8 a, s16x8 b, f32x4 c) {
    return __builtin_amdgcn_mfma_f32_16x16x32_bf16(a, b, c, 0, 0, 0);
}

__device__ inline ushort_t f2bf(float f) {   // RTNE float->bf16
    union { float f; unsigned u; } v; v.f = f;
    unsigned r = v.u + 0x7FFFu + ((v.u >> 16) & 1u);
    return (ushort_t)(r >> 16);
}
__device__ inline float bf2f(short s) {
    union { unsigned u; float f; } t; t.u = ((unsigned)(unsigned short)s) << 16; return t.f;
}
__device__ inline void cvt4(const float4 f, ushort_t* t) {
    t[0] = f2bf(f.x); t[1] = f2bf(f.y); t[2] = f2bf(f.z); t[3] = f2bf(f.w);
}
__device__ inline s16x8 pack8(const ushort_t* t) {
    s16x8 r;
    #pragma unroll
    for (int e = 0; e < 8; ++e) r[e] = (short)t[e];
    return r;
}

// XOR-swizzled LDS index for 64-u16-wide buffers: 16B chunk ^= (row & 7).
// Frag reads (chunk = 4ks+quad, row%8 = lanelo%8) become bank-conflict-free.
// Involution: physical chunk = logical chunk ^ (row&7) on BOTH write and read.
__device__ inline int lidx(int row, int chunk) {
    return row * 64 + ((chunk ^ (row & 7)) << 3);
}

// HBM -> LDS direct DMA, 16 B per lane. lds ptr must be wave-uniform
// (HW writes base + lane*16); global ptr is per-lane.
__device__ inline void gl_lds16(const ushort_t* g, ushort_t* l) {
    __builtin_amdgcn_global_load_lds(
        (const __attribute__((address_space(1))) unsigned*)g,
        (__attribute__((address_space(3))) unsigned*)l, 16, 0, 0);
}

// ---------------------------------------------------------------------------
// prep: blocks [0,2560) cast x->xb + pos->posb (row 2047 zeroed);
//       blocks [2560,2880) transpose+cast the 5 weight matrices into WT.
// ---------------------------------------------------------------------------
__global__ __launch_bounds__(256) void prep(
    const float* __restrict__ x, const float* __restrict__ pos,
    const float* __restrict__ W0, const float* __restrict__ W1,
    const float* __restrict__ W2, const float* __restrict__ W3,
    const float* __restrict__ W4,
    ushort_t* __restrict__ xb, ushort_t* __restrict__ posb,
    ushort_t* __restrict__ WT)
{
    __shared__ float T[64][68];
    const int bx = blockIdx.x;
    const int tid = threadIdx.x;
    if (bx < 2560) {
        const size_t N1 = (size_t)8192 * 512;
        size_t e = ((size_t)bx * 256 + tid) * 8;
        ushort_t tmp[8];
        if (e < N1) {
            const float4* s = (const float4*)(x + e);
            cvt4(s[0], tmp); cvt4(s[1], tmp + 4);
            *(s16x8*)(xb + e) = pack8(tmp);
        } else {
            size_t e2 = e - N1;                 // < 2048*512
            int row = (int)(e2 >> 9);
            if (row < 2047) {
                const float4* s = (const float4*)(pos + e2);
                cvt4(s[0], tmp); cvt4(s[1], tmp + 4);
            } else {
                #pragma unroll
                for (int i = 0; i < 8; ++i) tmp[i] = 0;
            }
            *(s16x8*)(posb + e2) = pack8(tmp);
        }
    } else {
        const int bz = bx - 2560;               // 0..319
        const int z = bz >> 6;                  // 0..4
        const int rem = bz & 63;
        const int n0 = (rem & 7) * 64, k0 = (rem >> 3) * 64;
        const float* W = (z == 0) ? W0 : (z == 1) ? W1
                       : (z == 2) ? W2 : (z == 3) ? W3 : W4;
        const int rr = tid >> 2, cc = (tid & 3) * 16;

        const float* src = W + (size_t)(k0 + rr) * 512 + n0 + cc;
        *(float4*)&T[rr][cc + 0]  = *(const float4*)(src);
        *(float4*)&T[rr][cc + 4]  = *(const float4*)(src + 4);
        *(float4*)&T[rr][cc + 8]  = *(const float4*)(src + 8);
        *(float4*)&T[rr][cc + 12] = *(const float4*)(src + 12);
        __syncthreads();

        ushort_t tmp[16];
        #pragma unroll
        for (int e = 0; e < 16; ++e) tmp[e] = f2bf(T[cc + e][rr]);
        ushort_t* dst = WT + ((size_t)z * 512 + n0 + rr) * 512 + k0 + cc;
        *(s16x8*)dst       = pack8(tmp);
        *(s16x8*)(dst + 8) = pack8(tmp + 8);
    }
}

// ---------------------------------------------------------------------------
// Fused QKV + P GEMM, 128x128 tiles, 4 waves, K=512.
// Double-buffered global_load_lds pipeline: ONE barrier per K-step; DMA for
// step k+1 is issued right after the barrier and drains at the next barrier,
// overlapping this step's 32 MFMAs + ds_reads. LDS 64 KB -> 2 blocks/CU.
// 1D grid 832 with bijective XCD swizzle (832 = 8*104).
// ---------------------------------------------------------------------------
__global__ __launch_bounds__(256) void gemm_qkvp(
    const ushort_t* __restrict__ xb, const ushort_t* __restrict__ posb,
    const ushort_t* __restrict__ WT,
    const float* __restrict__ bq, const float* __restrict__ bk,
    const float* __restrict__ bv, const float* __restrict__ pbu,
    ushort_t* __restrict__ Qu, ushort_t* __restrict__ Ko,
    ushort_t* __restrict__ VoT, ushort_t* __restrict__ Po)
{
    const int tid = threadIdx.x;
    const int flat = blockIdx.x;                  // 0..831
    const int nf = (flat & 7) * 104 + (flat >> 3);
    const int bxi = nf % 13, byi = nf / 13;

    const bool is_p = (bxi == 12);
    int row0, col0;
    const ushort_t* A;
    const ushort_t* B;
    if (is_p) {
        row0 = (byi >> 2) * 128;                 // 0..1920
        col0 = (byi & 3) * 128;                  // 0..384
        A = posb;
        B = WT + (size_t)3 * 512 * 512;
    } else {
        row0 = byi * 128;
        col0 = bxi * 128;
        A = xb;
        B = WT;                                  // col0 spans 0..1535 across sets
    }
    const int w = tid >> 6, lane = tid & 63;
    const int quad = lane >> 4, lanelo = lane & 15;
    const int wr = w >> 1, wc = w & 1;

    __shared__ ushort_t AsF[2][128 * 64];        // 32 KB (DMA dest, unpadded)
    __shared__ ushort_t BsF[2][128 * 64];        // 32 KB

    const int rs = tid >> 3, js = (tid & 7) * 8;
    const size_t lofs = (size_t)(tid & ~63) * 8; // wave-uniform LDS offset/256-blk

    f32x4 acc[4][4] = {};

    // prologue: stage K-step 0 into buf 0
    #pragma unroll
    for (int i = 0; i < 4; ++i) {
        gl_lds16(A + (size_t)(row0 + i * 32 + rs) * 512 + js,
                 AsF[0] + (size_t)i * 2048 + lofs);
        gl_lds16(B + (size_t)(col0 + i * 32 + rs) * 512 + js,
                 BsF[0] + (size_t)i * 2048 + lofs);
    }

    for (int kk = 0; kk < 8; ++kk) {
        const int cur = kk & 1;
        __syncthreads();                         // drains vmcnt: tile kk visible
        if (kk < 7) {                            // issue DMA for tile kk+1
            const int k1 = (kk + 1) * 64;
            #pragma unroll
            for (int i = 0; i < 4; ++i) {
                gl_lds16(A + (size_t)(row0 + i * 32 + rs) * 512 + k1 + js,
                         AsF[cur ^ 1] + (size_t)i * 2048 + lofs);
                gl_lds16(B + (size_t)(col0 + i * 32 + rs) * 512 + k1 + js,
                         BsF[cur ^ 1] + (size_t)i * 2048 + lofs);
            }
        }
        const ushort_t* Ac = AsF[cur];
        const ushort_t* Bc = BsF[cur];
        #pragma unroll
        for (int ks = 0; ks < 2; ++ks) {
            s16x8 af[4], bf[4];
            #pragma unroll
            for (int i = 0; i < 4; ++i)
                af[i] = *(const s16x8*)(Ac + (size_t)(64 * wr + 16 * i + lanelo) * 64 + ks * 32 + quad * 8);
            #pragma unroll
            for (int j = 0; j < 4; ++j)
                bf[j] = *(const s16x8*)(Bc + (size_t)(64 * wc + 16 * j + lanelo) * 64 + ks * 32 + quad * 8);
            #pragma unroll
            for (int i = 0; i < 4; ++i)
                #pragma unroll
                for (int j = 0; j < 4; ++j)
                    acc[i][j] = mfma16(af[i], bf[j], acc[i][j]);
        }
    }

    if (is_p) {
        #pragma unroll
        for (int j = 0; j < 4; ++j) {
            int c = col0 + 64 * wc + 16 * j + lanelo;
            #pragma unroll
            for (int i = 0; i < 4; ++i)
                #pragma unroll
                for (int r = 0; r < 4; ++r) {
                    int row = row0 + 64 * wr + 16 * i + 4 * quad + r;
                    Po[(size_t)row * 512 + c] = f2bf(acc[i][j][r]);
                }
        }
        return;
    }

    const int set = col0 >> 9;               // 0=Q,1=K,2=V (tile never straddles)
    const int cbase = (col0 & 511) + 64 * wc;
    if (set == 0) {
        #pragma unroll
        for (int j = 0; j < 4; ++j) {
            int c = cbase + 16 * j + lanelo;
            float vq = bq[c] + pbu[c];
            #pragma unroll
            for (int i = 0; i < 4; ++i)
                #pragma unroll
                for (int r = 0; r < 4; ++r) {
                    int row = row0 + 64 * wr + 16 * i + 4 * quad + r;
                    Qu[(size_t)row * 512 + c] = f2bf((acc[i][j][r] + vq) * KSCALE);
                }
        }
    } else if (set == 1) {
        #pragma unroll
        for (int j = 0; j < 4; ++j) {
            int c = cbase + 16 * j + lanelo;
            float vbk = bk[c];
            #pragma unroll
            for (int i = 0; i < 4; ++i)
                #pragma unroll
                for (int r = 0; r < 4; ++r) {
                    int row = row0 + 64 * wr + 16 * i + 4 * quad + r;
                    Ko[(size_t)row * 512 + c] = f2bf(acc[i][j][r] + vbk);
                }
        }
    } else {
        const int b_idx = row0 >> 10;
        #pragma unroll
        for (int j = 0; j < 4; ++j) {
            int c = cbase + 16 * j + lanelo;
            int hh = c >> 6, d = c & 63;
            float vbb = bv[c];
            #pragma unroll
            for (int i = 0; i < 4; ++i) {
                int t = (row0 & 1023) + 64 * wr + 16 * i + 4 * quad;
                ushort4 vp;
                vp.x = f2bf(acc[i][j][0] + vbb);
                vp.y = f2bf(acc[i][j][1] + vbb);
                vp.z = f2bf(acc[i][j][2] + vbb);
                vp.w = f2bf(acc[i][j][3] + vbb);
                *(ushort4*)(VoT + ((size_t)((b_idx * 8 + hh) * 64 + d)) * 1024 + t) = vp;
            }
        }
    }
}

// ---------------------------------------------------------------------------
// MFMA flash attention (R4-measured structure, exact):
//   block = 128 q-rows, 4 waves x 32 rows (2 row-tiles of 16 per wave).
//   K/V double-buffered + 256-slot circular P window -> ONE barrier/iter.
//   All staging via global_load_lds with pre-swizzled SOURCE. Grid 512, XCD
//   swizzle (one b per XCD). LDS 80 KB -> 2 blocks/CU; 124 VGPR.
// ---------------------------------------------------------------------------
__global__ __launch_bounds__(256, 2) void attn_mfma(
    const ushort_t* __restrict__ Qu,
    const ushort_t* __restrict__ Kb, const ushort_t* __restrict__ VT,
    const ushort_t* __restrict__ Pb,
    const float* __restrict__ pbu, const float* __restrict__ pbv,
    ushort_t* __restrict__ AOb)
{
    const int tid = threadIdx.x;
    const int flat = blockIdx.x;                  // 0..511
    const int nf = (flat & 7) * 64 + (flat >> 3); // bijective: 512 = 8*64
    const int t0 = (nf & 7) * 128;
    const int h  = (nf >> 3) & 7;
    const int b  = nf >> 6;

    const int w = tid >> 6, lane = tid & 63;
    const int quad = lane >> 4, lanelo = lane & 15;

    __shared__ ushort_t Kt[2 * 64 * 64];      // 16 KB  [s][d] swizzled, dbuf
    __shared__ ushort_t VtT[2 * 64 * 64];     // 16 KB  [d][s] swizzled, dbuf
    __shared__ ushort_t Pt[256 * 64];         // 32 KB  circular window, swizzled
    __shared__ ushort_t Ps[128 * 64];         // 16 KB  probs / O staging

    // Q for this wave's 32 rows (2 row-tiles of 16)
    const size_t qr0 = (size_t)(b * T_SEQ + t0 + 32 * w + lanelo) * 512 + h * 64;
    s16x8 qu0[2], qu1[2], qv0[2], qv1[2];
    qu0[0] = *(const s16x8*)(Qu + qr0 + quad * 8);
    qu0[1] = *(const s16x8*)(Qu + qr0 + 32 + quad * 8);
    qu1[0] = *(const s16x8*)(Qu + qr0 + (size_t)16 * 512 + quad * 8);
    qu1[1] = *(const s16x8*)(Qu + qr0 + (size_t)16 * 512 + 32 + quad * 8);
    // qv = qu + (pbv - pbu)*KSCALE  (per-k constant; k = ks*32 + quad*8 + e)
    #pragma unroll
    for (int e = 0; e < 8; ++e) {
        int k0i = h * 64 + quad * 8 + e;
        float d0 = (pbv[k0i] - pbu[k0i]) * KSCALE;
        float d1 = (pbv[k0i + 32] - pbu[k0i + 32]) * KSCALE;
        qv0[0][e] = (short)f2bf(bf2f(qu0[0][e]) + d0);
        qv0[1][e] = (short)f2bf(bf2f(qu0[1][e]) + d1);
        qv1[0][e] = (short)f2bf(bf2f(qu1[0][e]) + d0);
        qv1[1][e] = (short)f2bf(bf2f(qu1[1][e]) + d1);
    }

    f32x4 acc_o[2][4] = {};
    float l_part[2][4] = {{0.f,0.f,0.f,0.f},{0.f,0.f,0.f,0.f}};

    const ushort_t* VTbh = VT + ((size_t)((b * 8 + h) * 64)) * 1024;
    const ushort_t* Kbh  = Kb + (size_t)b * T_SEQ * 512 + (size_t)h * 64;
    const int pr_base = 960 - t0;               // in [64, 960], mult of 64

    const int sr = tid >> 3;                    // staging helpers (inline below)

    // ---- prologue: DMA iter-0 K/V (buf 0) + 192-row P window ----
    {
        #pragma unroll
        for (int i = 0; i < 2; ++i) {
            const int L = i * 256 + tid;
            const int r = L >> 3;
            const int ch = (L & 7) ^ (r & 7);    // inverse-swizzled source
            gl_lds16(Kbh + (size_t)r * 512 + ch * 8,
                     Kt + (size_t)(i * 256 + (tid & ~63)) * 8);
            gl_lds16(VTbh + (size_t)r * 1024 + ch * 8,
                     VtT + (size_t)(i * 256 + (tid & ~63)) * 8);
        }
        const int g0p = pr_base - 64;            // >= 0, mult of 64
        #pragma unroll
        for (int i = 0; i < 6; ++i) {
            const int L = i * 256 + tid;
            const int gr = g0p + (L >> 3);
            const int ch = (L & 7) ^ (gr & 7);
            const int sgb = (g0p + ((i * 256 + (tid & ~63)) >> 3)) & 255; // wave-uniform
            gl_lds16(Pb + (size_t)gr * 512 + h * 64 + ch * 8,
                     Pt + (size_t)sgb * 64);
        }
    }
    __syncthreads();                             // vmcnt drained by compiler

    for (int it = 0; it < 16; ++it) {
        const int s0 = it * 64;
        const int cur = it & 1;

        // ---- issue next-tile DMA into idle buffers (drains at end barrier,
        //      latency covered by this iteration's compute) ----
        if (it < 15) {
            ushort_t* Kn = Kt + (cur ^ 1) * 4096;
            ushort_t* Vn = VtT + (cur ^ 1) * 4096;
            const int sn = s0 + 64;
            #pragma unroll
            for (int i = 0; i < 2; ++i) {
                const int L = i * 256 + tid;
                const int r = L >> 3;
                const int ch = (L & 7) ^ (r & 7);
                gl_lds16(Kbh + (size_t)(sn + r) * 512 + ch * 8,
                         Kn + (size_t)(i * 256 + (tid & ~63)) * 8);
                gl_lds16(VTbh + (size_t)r * 1024 + sn + ch * 8,
                         Vn + (size_t)(i * 256 + (tid & ~63)) * 8);
            }
            const int g0 = pr_base + s0 + 128;   // rows g0..g0+63 (max 2047)
            #pragma unroll
            for (int i = 0; i < 2; ++i) {
                const int L = i * 256 + tid;
                const int gr = g0 + (L >> 3);
                const int ch = (L & 7) ^ (gr & 7);
                const int sgb = (g0 + ((i * 256 + (tid & ~63)) >> 3)) & 255;
                gl_lds16(Pb + (size_t)gr * 512 + h * 64 + ch * 8,
                         Pt + (size_t)sgb * 64);
            }
        }

        const ushort_t* Kc = Kt + cur * 4096;
        const ushort_t* Vc = VtT + cur * 4096;
        const int pb = (pr_base + s0) & 255;     // window base slot

        // ---- scores: content (8 MFMA/ks) + pos band (10 MFMA/ks, 6 loads) ----
        f32x4 acc_c[2][4] = {};
        f32x4 acc_g[2][5] = {};
        __builtin_amdgcn_s_setprio(1);
        #pragma unroll
        for (int ks = 0; ks < 2; ++ks) {
            #pragma unroll
            for (int tn = 0; tn < 4; ++tn) {
                s16x8 kf = *(const s16x8*)(Kc + lidx(tn * 16 + lanelo, 4 * ks + quad));
                acc_c[0][tn] = mfma16(qu0[ks], kf, acc_c[0][tn]);
                acc_c[1][tn] = mfma16(qu1[ks], kf, acc_c[1][tn]);
            }
            #pragma unroll
            for (int m = 0; m < 6; ++m) {        // loaded tile = (2-2w)+m
                int prow = (pb + 256 + (2 - 2 * w + m) * 16 + lanelo) & 255;
                s16x8 pf = *(const s16x8*)(Pt + lidx(prow, 4 * ks + quad));
                if (m >= 1) acc_g[0][m - 1] = mfma16(qv0[ks], pf, acc_g[0][m - 1]);
                if (m <= 4) acc_g[1][m]     = mfma16(qv1[ks], pf, acc_g[1][m]);
            }
        }
        __builtin_amdgcn_s_setprio(0);

        // ---- band extraction + exp2 (no max; softmax shift-invariant) ----
        #pragma unroll
        for (int rt = 0; rt < 2; ++rt) {
            #pragma unroll
            for (int r = 0; r < 4; ++r) {
                const int u = lanelo + 15 - 4 * quad - r;   // 0..30
                const int srcl = (quad << 4) | (u & 15);
                const bool hi = (u >= 16);
                #pragma unroll
                for (int tn = 0; tn < 4; ++tn) {
                    float v0 = __shfl(acc_g[rt][tn][r], srcl);
                    float v1 = __shfl(acc_g[rt][tn + 1][r], srcl);
                    float e = __builtin_amdgcn_exp2f(acc_c[rt][tn][r] + (hi ? v1 : v0));
                    l_part[rt][r] += e;
                    const int pr = 32 * w + 16 * rt + 4 * quad + r;
                    const int ch = 2 * tn + (lanelo >> 3);
                    Ps[pr * 64 + ((ch ^ (pr & 7)) << 3) + (lanelo & 7)] = f2bf(e);
                }
            }
        }
        asm volatile("s_waitcnt lgkmcnt(0)" ::: "memory");

        // ---- PV: A = probs (wave-private Ps rows), B = V^T tile ----
        __builtin_amdgcn_s_setprio(1);
        #pragma unroll
        for (int ks = 0; ks < 2; ++ks) {
            s16x8 af0 = *(const s16x8*)(Ps + lidx(32 * w + lanelo, 4 * ks + quad));
            s16x8 af1 = *(const s16x8*)(Ps + lidx(32 * w + 16 + lanelo, 4 * ks + quad));
            #pragma unroll
            for (int dt = 0; dt < 4; ++dt) {
                s16x8 vb = *(const s16x8*)(Vc + lidx(dt * 16 + lanelo, 4 * ks + quad));
                acc_o[0][dt] = mfma16(af0, vb, acc_o[0][dt]);
                acc_o[1][dt] = mfma16(af1, vb, acc_o[1][dt]);
            }
        }
        __builtin_amdgcn_s_setprio(0);

        __syncthreads();   // single barrier: reads done + staged DMA drained
    }

    // single end-of-kernel l reduction (16 lanes per row group)
    float inv[2][4];
    #pragma unroll
    for (int rt = 0; rt < 2; ++rt)
        #pragma unroll
        for (int r = 0; r < 4; ++r) {
            float l = l_part[rt][r];
            l += __shfl_xor(l, 1);
            l += __shfl_xor(l, 2);
            l += __shfl_xor(l, 4);
            l += __shfl_xor(l, 8);
            inv[rt][r] = 1.0f / l;
        }

    // epilogue: stage O into Ps (bf16, swizzled), then coalesced vector stores
    #pragma unroll
    for (int rt = 0; rt < 2; ++rt)
        #pragma unroll
        for (int dt = 0; dt < 4; ++dt)
            #pragma unroll
            for (int r = 0; r < 4; ++r) {
                const int pr = 32 * w + 16 * rt + 4 * quad + r;
                const int ch = 2 * dt + (lanelo >> 3);
                Ps[pr * 64 + ((ch ^ (pr & 7)) << 3) + (lanelo & 7)] =
                    f2bf(acc_o[rt][dt][r] * inv[rt][r]);
            }
    __syncthreads();
    {
        const int row = tid >> 1, cb = (tid & 1) * 4;
        ushort_t* dst = AOb + (size_t)(b * T_SEQ + t0 + row) * 512 + h * 64 + cb * 8;
        #pragma unroll
        for (int c = 0; c < 4; ++c)
            *(s16x8*)(dst + c * 8) = *(const s16x8*)(Ps + lidx(row, cb + c));
    }
}

// ---------------------------------------------------------------------------
// Final projection: out = AOb @ WoT + bo  (A bf16, fp32 out), 128x128 tiles,
// double-buffered global_load_lds pipeline (one barrier per K-step).
// 1D grid 256 with XCD swizzle (256 = 8*32).
// ---------------------------------------------------------------------------
__global__ __launch_bounds__(256) void gemm_out(
    const ushort_t* __restrict__ A, const ushort_t* __restrict__ WTo,
    const float* __restrict__ bias, float* __restrict__ C)
{
    const int tid = threadIdx.x;
    const int flat = blockIdx.x;                  // 0..255
    const int nfi = (flat & 7) * 32 + (flat >> 3);
    const int col0 = (nfi & 3) * 128;
    const int row0 = (nfi >> 2) * 128;
    const int w = tid >> 6, lane = tid & 63;
    const int quad = lane >> 4, lanelo = lane & 15;
    const int wr = w >> 1, wc = w & 1;

    __shared__ ushort_t AsF[2][128 * 64];
    __shared__ ushort_t BsF[2][128 * 64];

    const int rs = tid >> 3, js = (tid & 7) * 8;
    const size_t lofs = (size_t)(tid & ~63) * 8;

    f32x4 acc[4][4] = {};

    // prologue: stage K-step 0 into buf 0
    #pragma unroll
    for (int i = 0; i < 4; ++i) {
        gl_lds16(A + (size_t)(row0 + i * 32 + rs) * 512 + js,
                 AsF[0] + (size_t)i * 2048 + lofs);
        gl_lds16(WTo + (size_t)(col0 + i * 32 + rs) * 512 + js,
                 BsF[0] + (size_t)i * 2048 + lofs);
    }

    for (int kk = 0; kk < 8; ++kk) {
        const int cur = kk & 1;
        __syncthreads();
        if (kk < 7) {
            const int k1 = (kk + 1) * 64;
            #pragma unroll
            for (int i = 0; i < 4; ++i) {
                gl_lds16(A + (size_t)(row0 + i * 32 + rs) * 512 + k1 + js,
                         AsF[cur ^ 1] + (size_t)i * 2048 + lofs);
                gl_lds16(WTo + (size_t)(col0 + i * 32 + rs) * 512 + k1 + js,
                         BsF[cur ^ 1] + (size_t)i * 2048 + lofs);
            }
        }
        const ushort_t* Ac = AsF[cur];
        const ushort_t* Bc = BsF[cur];
        #pragma unroll
        for (int ks = 0; ks < 2; ++ks) {
            s16x8 af[4], bf[4];
            #pragma unroll
            for (int i = 0; i < 4; ++i)
                af[i] = *(const s16x8*)(Ac + (size_t)(64 * wr + 16 * i + lanelo) * 64 + ks * 32 + quad * 8);
            #pragma unroll
            for (int j = 0; j < 4; ++j)
                bf[j] = *(const s16x8*)(Bc + (size_t)(64 * wc + 16 * j + lanelo) * 64 + ks * 32 + quad * 8);
            #pragma unroll
            for (int i = 0; i < 4; ++i)
                #pragma unroll
                for (int j = 0; j < 4; ++j)
                    acc[i][j] = mfma16(af[i], bf[j], acc[i][j]);
        }
    }

    #pragma unroll
    for (int j = 0; j < 4; ++j) {
        int c = col0 + 64 * wc + 16 * j + lanelo;
        float vb = bias[c];
        #pragma unroll
        for (int i = 0; i < 4; ++i)
            #pragma unroll
            for (int r = 0; r < 4; ++r) {
                int row = row0 + 64 * wr + 16 * i + 4 * quad + r;
                C[(size_t)row * 512 + c] = acc[i][j][r] + vb;
            }
    }
}

// ---------------------------------------------------------------------------
extern "C" void kernel_launch(void* const* d_in, const int* in_sizes, int n_in,
                              void* d_out, int out_size, void* d_ws, size_t ws_size,
                              hipStream_t stream) {
    const float* x       = (const float*)d_in[0];
    const float* pos_enc = (const float*)d_in[1];
    const float* Wq      = (const float*)d_in[2];
    const float* bq      = (const float*)d_in[3];
    const float* Wk      = (const float*)d_in[4];
    const float* bk      = (const float*)d_in[5];
    const float* Wv      = (const float*)d_in[6];
    const float* bv      = (const float*)d_in[7];
    const float* Wpos    = (const float*)d_in[8];
    const float* pbu     = (const float*)d_in[9];
    const float* pbv     = (const float*)d_in[10];
    const float* Wo      = (const float*)d_in[11];
    const float* bo      = (const float*)d_in[12];
    float* out = (float*)d_out;

    const size_t M  = 8 * T_SEQ;                 // 8192
    const size_t SZ = M * D_MODEL;               // 4,194,304

    char* ws = (char*)d_ws;
    ushort_t* xb   = (ushort_t*)ws;              ws += SZ * 2;
    ushort_t* posb = (ushort_t*)ws;              ws += (size_t)2048 * 512 * 2;
    ushort_t* Qu_b = (ushort_t*)ws;              ws += SZ * 2;
    ushort_t* K_b  = (ushort_t*)ws;              ws += SZ * 2;
    ushort_t* VT_b = (ushort_t*)ws;              ws += SZ * 2;
    ushort_t* P_b  = (ushort_t*)ws;              ws += (size_t)2048 * 512 * 2;
    ushort_t* WT   = (ushort_t*)ws;              ws += (size_t)5 * 512 * 512 * 2;
    ushort_t* AOb  = (ushort_t*)ws;              ws += SZ * 2;

    dim3 blk(256);

    hipLaunchKernelGGL(prep, dim3(2880), blk, 0, stream,
                       x, pos_enc, Wq, Wk, Wv, Wpos, Wo, xb, posb, WT);

    hipLaunchKernelGGL(gemm_qkvp, dim3(832), blk, 0, stream,
                       xb, posb, WT, bq, bk, bv, pbu,
                       Qu_b, K_b, VT_b, P_b);

    hipLaunchKernelGGL(attn_mfma, dim3(512), blk, 0, stream,
                       Qu_b, K_b, VT_b, P_b, pbu, pbv, AOb);

    hipLaunchKernelGGL(gemm_out, dim3(256), blk, 0, stream,
                       AOb, WT + (size_t)4 * 512 * 512, bo, out);
}